// Round 9
// baseline (273.782 us; speedup 1.0000x reference)
//
#include <hip/hip_runtime.h>
#include <hip/hip_cooperative_groups.h>

namespace cg = cooperative_groups;

#define B 4
#define C 256
#define CI 128
#define NPIX 3136      // 56*56 = 49 * 64
#define BN_EPS_F 1e-5f
#define INVN (1.0f / 3136.0f)

typedef float f4 __attribute__((ext_vector_type(4)));
typedef float f32x4 __attribute__((ext_vector_type(4)));
typedef short short8 __attribute__((ext_vector_type(8)));
typedef short short4v __attribute__((ext_vector_type(4)));
typedef unsigned int u32;
typedef u32 u32x4 __attribute__((ext_vector_type(4)));

__device__ inline short f2bf(float f) {
    u32 u = __builtin_bit_cast(u32, f);
    u32 r = (u + 0x7FFFu + ((u >> 16) & 1u)) >> 16;
    return (short)r;
}
__device__ inline float bf2f(short v) {
    u32 u = ((u32)(unsigned short)v) << 16;
    return __builtin_bit_cast(float, u);
}
__device__ inline u32 pk2(float a, float b) {
    return (u32)(unsigned short)f2bf(a) | ((u32)(unsigned short)f2bf(b) << 16);
}
__device__ inline short8 pack8(f4 v0, f4 v1) {
    u32x4 u = { pk2(v0[0], v0[1]), pk2(v0[2], v0[3]), pk2(v1[0], v1[1]), pk2(v1[2], v1[3]) };
    return __builtin_bit_cast(short8, u);
}

struct Prm {
    const float *x, *wtheta, *btheta, *wphi, *bphi, *wg, *bg, *wrec, *brec;
    const float *gamma, *beta, *mean, *var;
    float *out;
    float *spart, *slv, *qarr, *Ls, *pv, *tgg, *wtg, *bnc, *swt, *scal, *bias5;
    short *xbf, *xT, *Gbf, *Ut, *T2t, *T3, *WtT, *W5;
};

// One cooperative kernel: 256 blocks x 256 threads, 7 phases, 6 grid syncs.
__global__ __launch_bounds__(256) void mono_kernel(Prm p) {
    cg::grid_group grid = cg::this_grid();
    __shared__ char smem[8448];
    int bid = blockIdx.x;
    int t = threadIdx.x, lane = t & 63, wid = t >> 6;
    int lm = lane & 15, lk = (lane >> 4) * 8, r0q = (lane >> 4) * 4;

    // ================= P1: prep — xbf, xT, spart (784 tiles, grid-stride) ======
    for (int tile = bid; tile < 784; tile += 256) {
        int nb = tile % 49, cb = (tile / 49) & 3, b = tile / 196;
        int n0 = nb * 64, c0 = cb * 64;
        short (*lds)[65] = (short(*)[65])smem;
        int nf = (t & 15) * 4, cr = t >> 4;
        float psum[4];
#pragma unroll
        for (int it = 0; it < 4; ++it) {
            int c = cr + 16 * it;
            f4 v = *(const f4*)&p.x[((size_t)(b * C + c0 + c)) * NPIX + n0 + nf];
            short4v s4;
            float ps = 0.f;
#pragma unroll
            for (int i = 0; i < 4; ++i) { s4[i] = f2bf(v[i]); ps += v[i]; }
            psum[it] = ps;
            *(short4v*)&p.xbf[((size_t)(b * C + c0 + c)) * NPIX + n0 + nf] = s4;
#pragma unroll
            for (int i = 0; i < 4; ++i) lds[nf + i][c] = s4[i];
        }
#pragma unroll
        for (int it = 0; it < 4; ++it) {
            float ps = psum[it];
#pragma unroll
            for (int m = 8; m >= 1; m >>= 1) ps += __shfl_xor(ps, m, 64);
            if ((t & 15) == 0)
                p.spart[(size_t)(b * C + c0 + cr + 16 * it) * 49 + nb] = ps;
        }
        __syncthreads();
#pragma unroll
        for (int it = 0; it < 4; ++it) {
            int n = cr + 16 * it;
            short4v s4;
#pragma unroll
            for (int i = 0; i < 4; ++i) s4[i] = lds[n][nf + i];
            *(short4v*)&p.xT[((size_t)b * NPIX + n0 + n) * C + c0 + nf] = s4;
        }
        __syncthreads();
    }
    grid.sync();

    // ================= P2: xxt (0..63) | batch vectors (64..67) | scalars (68)
    // | WθT transpose (69..84) ==================================================
    if (bid < 64) {
        int b = bid >> 4, r = bid & 15;
        int ibase = (r >> 2) * 64 + (wid >> 1) * 32;
        int jbase = (r & 3) * 64 + (wid & 1) * 32;
        const short* A0 = p.xbf + ((size_t)(b * C) + ibase + lm) * NPIX + lk;
        const short* B0 = p.xbf + ((size_t)(b * C) + jbase + lm) * NPIX + lk;
        f32x4 acc[2][2] = {};
        for (int k = 0; k < NPIX; k += 32) {
            short8 av[2], bv[2];
#pragma unroll
            for (int mi = 0; mi < 2; ++mi) av[mi] = *(const short8*)(A0 + (size_t)mi * 16 * NPIX + k);
#pragma unroll
            for (int nj = 0; nj < 2; ++nj) bv[nj] = *(const short8*)(B0 + (size_t)nj * 16 * NPIX + k);
#pragma unroll
            for (int mi = 0; mi < 2; ++mi)
#pragma unroll
                for (int nj = 0; nj < 2; ++nj)
                    acc[mi][nj] = __builtin_amdgcn_mfma_f32_16x16x32_bf16(av[mi], bv[nj], acc[mi][nj], 0, 0, 0);
        }
        short* Gb = p.Gbf + (size_t)b * C * C;
#pragma unroll
        for (int mi = 0; mi < 2; ++mi)
#pragma unroll
            for (int rr = 0; rr < 4; ++rr)
#pragma unroll
                for (int nj = 0; nj < 2; ++nj)
                    Gb[(ibase + mi * 16 + r0q + rr) * C + jbase + nj * 16 + lm] = f2bf(acc[mi][nj][rr]);
    } else if (bid < 68) {
        int b = bid - 64;
        float* sl_l = (float*)smem;          // 256 f32
        float* uv_l = sl_l + 256;            // 256 f32 (uu | vv)
        const float* sp = p.spart + (size_t)(b * C + t) * 49;
        float sv = 0.f;
        for (int i = 0; i < 49; ++i) sv += sp[i];
        sl_l[t] = sv;
        p.slv[b * C + t] = sv;
        __syncthreads();
        {
            int i = t & 127;
            const float* wrow = ((t < 128) ? p.wphi : p.wg) + (size_t)i * C;
            float a = 0.f;
#pragma unroll 4
            for (int c4 = 0; c4 < C; c4 += 4) {
                f4 w = *(const f4*)&wrow[c4];
                a += w[0] * sl_l[c4] + w[1] * sl_l[c4 + 1] + w[2] * sl_l[c4 + 2] + w[3] * sl_l[c4 + 3];
            }
            uv_l[t] = a;
        }
        __syncthreads();
        float qa = 0.f;
        for (int i = 0; i < CI; ++i) qa = fmaf(uv_l[i], p.wtheta[i * C + t], qa);
        p.qarr[b * C + t] = qa;
        float inv_t = p.gamma[t] * rsqrtf(p.var[t] + BN_EPS_F);
        float a = 0.f;
#pragma unroll 4
        for (int j4 = 0; j4 < CI; j4 += 4) {
            f4 w = *(const f4*)&p.wrec[t * CI + j4];
            a += w[0] * uv_l[128 + j4] + w[1] * uv_l[129 + j4]
               + w[2] * uv_l[130 + j4] + w[3] * uv_l[131 + j4];
        }
        p.Ls[b * C + t] = inv_t * a;
    } else if (bid == 68) {
        float* red = (float*)smem;
        float inv_t = p.gamma[t] * rsqrtf(p.var[t] + BN_EPS_F);
        float accp = 0.f;
#pragma unroll 4
        for (int j4 = 0; j4 < CI; j4 += 4) {
            f4 w = *(const f4*)&p.wrec[t * CI + j4];
            f4 g4 = *(const f4*)&p.bg[j4];
            accp += w[0] * g4[0] + w[1] * g4[1] + w[2] * g4[2] + w[3] * g4[3];
        }
        p.pv[t] = inv_t * accp;
        float at = 0.f, aw = 0.f;
        for (int i = 0; i < CI; ++i) {
            at = fmaf(p.wtheta[i * C + t], p.bphi[i], at);
            aw = fmaf(p.wphi[i * C + t], p.btheta[i], aw);
        }
        p.tgg[t] = at;
        p.wtg[t] = aw;
        p.bnc[t] = inv_t * p.brec[t] + p.beta[t] - p.mean[t] * inv_t;
        float cp = (t < CI) ? p.bphi[t] * p.btheta[t] : 0.f;
#pragma unroll
        for (int m = 32; m >= 1; m >>= 1) cp += __shfl_xor(cp, m, 64);
        if (lane == 0) red[wid] = cp;
        __syncthreads();
        if (t == 0) p.scal[0] = red[0] + red[1] + red[2] + red[3];
    } else if (bid < 85) {
        int base = (bid - 69) * 2048;
#pragma unroll
        for (int rep = 0; rep < 8; ++rep) {
            int idx = base + rep * 256 + t;
            int cp = idx & 255, i = idx >> 8;
            p.WtT[cp * CI + i] = f2bf(p.wtheta[i * C + cp]);
        }
    }
    grid.sync();

    // ================= P3a: Ut[i][c] = sum_c2 Wφ[i][c2]·G[c][c2] (32) | swt (32..35)
    if (bid < 32) {
        int b = bid >> 3, q = bid & 7;
        int m0 = (q & 1) * 64 + (wid >> 1) * 32;   // i
        int n0 = (q >> 1) * 64 + (wid & 1) * 32;   // c
        const short* Gb = p.Gbf + (size_t)b * C * C;
        f32x4 acc[2][2] = {};
        for (int k = 0; k < C; k += 32) {
            short8 av[2], bv[2];
#pragma unroll
            for (int mi = 0; mi < 2; ++mi) {
                const float* w = p.wphi + (size_t)(m0 + mi * 16 + lm) * C + k + lk;
                av[mi] = pack8(*(const f4*)w, *(const f4*)(w + 4));
            }
#pragma unroll
            for (int nj = 0; nj < 2; ++nj)
                bv[nj] = *(const short8*)(Gb + (size_t)(n0 + nj * 16 + lm) * C + k + lk);
#pragma unroll
            for (int mi = 0; mi < 2; ++mi)
#pragma unroll
                for (int nj = 0; nj < 2; ++nj)
                    acc[mi][nj] = __builtin_amdgcn_mfma_f32_16x16x32_bf16(av[mi], bv[nj], acc[mi][nj], 0, 0, 0);
        }
        short* Utb = p.Ut + (size_t)b * CI * C;
#pragma unroll
        for (int mi = 0; mi < 2; ++mi)
#pragma unroll
            for (int rr = 0; rr < 4; ++rr)
#pragma unroll
                for (int nj = 0; nj < 2; ++nj)
                    Utb[(m0 + mi * 16 + r0q + rr) * C + n0 + nj * 16 + lm] = f2bf(acc[mi][nj][rr]);
    } else if (bid < 36) {
        int b = bid - 32;
        float* red = (float*)smem;
        float part = p.slv[b * C + t] * p.wtg[t];
#pragma unroll
        for (int m = 32; m >= 1; m >>= 1) part += __shfl_xor(part, m, 64);
        if (lane == 0) red[wid] = part;
        __syncthreads();
        if (t == 0) p.swt[b] = red[0] + red[1] + red[2] + red[3];
    }
    grid.sync();

    // ================= P3b: T2t[i2][i] = sum_c Ut[i2][c]·Wg[i][c] (16 blocks) ====
    if (bid < 16) {
        int b = bid >> 2, q = bid & 3;
        int m0 = (q >> 1) * 64 + (wid >> 1) * 32;   // i2
        int n0 = (q & 1) * 64 + (wid & 1) * 32;     // i
        const short* Utb = p.Ut + (size_t)b * CI * C;
        f32x4 acc[2][2] = {};
        for (int k = 0; k < C; k += 32) {
            short8 av[2], bv[2];
#pragma unroll
            for (int mi = 0; mi < 2; ++mi)
                av[mi] = *(const short8*)(Utb + (size_t)(m0 + mi * 16 + lm) * C + k + lk);
#pragma unroll
            for (int nj = 0; nj < 2; ++nj) {
                const float* w = p.wg + (size_t)(n0 + nj * 16 + lm) * C + k + lk;
                bv[nj] = pack8(*(const f4*)w, *(const f4*)(w + 4));
            }
#pragma unroll
            for (int mi = 0; mi < 2; ++mi)
#pragma unroll
                for (int nj = 0; nj < 2; ++nj)
                    acc[mi][nj] = __builtin_amdgcn_mfma_f32_16x16x32_bf16(av[mi], bv[nj], acc[mi][nj], 0, 0, 0);
        }
        short* T2b = p.T2t + (size_t)b * CI * CI;
#pragma unroll
        for (int mi = 0; mi < 2; ++mi)
#pragma unroll
            for (int rr = 0; rr < 4; ++rr)
#pragma unroll
                for (int nj = 0; nj < 2; ++nj)
                    T2b[(m0 + mi * 16 + r0q + rr) * CI + n0 + nj * 16 + lm] = f2bf(acc[mi][nj][rr]);
    }
    grid.sync();

    // ================= P3c: T3[o][i2] = sum_i wrec[o][i]·T2t[i2][i] (32 blocks) ==
    if (bid < 32) {
        int b = bid >> 3, q = bid & 7;
        int m0 = (q >> 1) * 64 + (wid >> 1) * 32;   // o
        int n0 = (q & 1) * 64 + (wid & 1) * 32;     // i2
        const short* T2b = p.T2t + (size_t)b * CI * CI;
        f32x4 acc[2][2] = {};
        for (int k = 0; k < CI; k += 32) {
            short8 av[2], bv[2];
#pragma unroll
            for (int mi = 0; mi < 2; ++mi) {
                const float* w = p.wrec + (size_t)(m0 + mi * 16 + lm) * CI + k + lk;
                av[mi] = pack8(*(const f4*)w, *(const f4*)(w + 4));
            }
#pragma unroll
            for (int nj = 0; nj < 2; ++nj)
                bv[nj] = *(const short8*)(T2b + (size_t)(n0 + nj * 16 + lm) * CI + k + lk);
#pragma unroll
            for (int mi = 0; mi < 2; ++mi)
#pragma unroll
                for (int nj = 0; nj < 2; ++nj)
                    acc[mi][nj] = __builtin_amdgcn_mfma_f32_16x16x32_bf16(av[mi], bv[nj], acc[mi][nj], 0, 0, 0);
        }
        short* T3b = p.T3 + (size_t)b * C * CI;
#pragma unroll
        for (int mi = 0; mi < 2; ++mi)
#pragma unroll
            for (int rr = 0; rr < 4; ++rr)
#pragma unroll
                for (int nj = 0; nj < 2; ++nj)
                    T3b[(m0 + mi * 16 + r0q + rr) * CI + n0 + nj * 16 + lm] = f2bf(acc[mi][nj][rr]);
    }
    grid.sync();

    // ================= P3d: W5 (0..63) + bias5 (64..67) =========================
    if (bid < 64) {
        int b = bid >> 4, q = bid & 15;
        int m0 = (q >> 2) * 64 + (wid >> 1) * 32;   // o
        int n0 = (q & 3) * 64 + (wid & 1) * 32;     // c'
        const short* T3b = p.T3 + (size_t)b * C * CI;
        f32x4 acc[2][2] = {};
        for (int k = 0; k < CI; k += 32) {
            short8 av[2], bv[2];
#pragma unroll
            for (int mi = 0; mi < 2; ++mi)
                av[mi] = *(const short8*)(T3b + (size_t)(m0 + mi * 16 + lm) * CI + k + lk);
#pragma unroll
            for (int nj = 0; nj < 2; ++nj)
                bv[nj] = *(const short8*)(p.WtT + (size_t)(n0 + nj * 16 + lm) * CI + k + lk);
#pragma unroll
            for (int mi = 0; mi < 2; ++mi)
#pragma unroll
                for (int nj = 0; nj < 2; ++nj)
                    acc[mi][nj] = __builtin_amdgcn_mfma_f32_16x16x32_bf16(av[mi], bv[nj], acc[mi][nj], 0, 0, 0);
        }
        short* W5b = p.W5 + (size_t)b * C * C;
#pragma unroll
        for (int mi = 0; mi < 2; ++mi) {
#pragma unroll
            for (int rr = 0; rr < 4; ++rr) {
                int o = m0 + mi * 16 + r0q + rr;
                float inv_o = p.gamma[o] * rsqrtf(p.var[o] + BN_EPS_F);
                float po = p.pv[o], ls = p.Ls[b * C + o];
#pragma unroll
                for (int nj = 0; nj < 2; ++nj) {
                    int cp2 = n0 + nj * 16 + lm;
                    float tgc = p.tgg[cp2];
                    float w5 = INVN * inv_o * acc[mi][nj][rr]
                             + po * (INVN * p.qarr[b * C + cp2] + tgc)
                             + INVN * ls * tgc;
                    W5b[o * C + cp2] = f2bf(w5);
                }
            }
        }
    } else if (bid < 68) {
        int b = bid - 64;
        const short* T3b = p.T3 + (size_t)b * C * CI;
        float dot = 0.f;
        for (int i8 = 0; i8 < CI; i8 += 8) {
            short8 v = *(const short8*)(T3b + (size_t)t * CI + i8);
#pragma unroll
            for (int j = 0; j < 8; ++j) dot += bf2f(v[j]) * p.btheta[i8 + j];
        }
        float inv_t = p.gamma[t] * rsqrtf(p.var[t] + BN_EPS_F);
        p.bias5[b * C + t] = INVN * inv_t * dot + INVN * p.swt[b] * p.pv[t]
                           + p.scal[0] * (INVN * p.Ls[b * C + t] + p.pv[t])
                           + p.bnc[t];
    }
    grid.sync();

    // ================= P4: out = W5·x + bias5 + x (196 blocks) ==================
    if (bid < 196) {
        int b = bid / 49, n0 = (bid % 49) * 64;
        int obase = wid * 64;
        const short* A0 = p.W5 + ((size_t)(b * C) + obase + lm) * C + lk;
        const short* B0 = p.xT + ((size_t)b * NPIX + n0 + lm) * C + lk;
        f32x4 acc[4][4] = {};
#pragma unroll
        for (int k = 0; k < C; k += 32) {
            short8 av[4], bv[4];
#pragma unroll
            for (int mi = 0; mi < 4; ++mi) av[mi] = *(const short8*)(A0 + mi * 16 * C + k);
#pragma unroll
            for (int nj = 0; nj < 4; ++nj) bv[nj] = *(const short8*)(B0 + nj * 16 * C + k);
#pragma unroll
            for (int mi = 0; mi < 4; ++mi)
#pragma unroll
                for (int nj = 0; nj < 4; ++nj)
                    acc[mi][nj] = __builtin_amdgcn_mfma_f32_16x16x32_bf16(av[mi], bv[nj], acc[mi][nj], 0, 0, 0);
        }
#pragma unroll
        for (int mi = 0; mi < 4; ++mi) {
#pragma unroll
            for (int rr = 0; rr < 4; ++rr) {
                int o = obase + mi * 16 + r0q + rr;
                float bias = p.bias5[b * C + o];
                const float* xrow = p.x + ((size_t)(b * C + o)) * NPIX;
                float* orow = p.out + ((size_t)(b * C + o)) * NPIX;
#pragma unroll
                for (int nj = 0; nj < 4; ++nj) {
                    int n = n0 + nj * 16 + lm;
                    orow[n] = acc[mi][nj][rr] + bias + xrow[n];
                }
            }
        }
    }
}

extern "C" void kernel_launch(void* const* d_in, const int* in_sizes, int n_in,
                              void* d_out, int out_size, void* d_ws, size_t ws_size,
                              hipStream_t stream) {
    char* wsb = (char*)d_ws;
    Prm prm;
    prm.x       = (const float*)d_in[0];
    prm.wtheta  = (const float*)d_in[1];
    prm.btheta  = (const float*)d_in[2];
    prm.wphi    = (const float*)d_in[3];
    prm.bphi    = (const float*)d_in[4];
    prm.wg      = (const float*)d_in[5];
    prm.bg      = (const float*)d_in[6];
    prm.wrec    = (const float*)d_in[7];
    prm.brec    = (const float*)d_in[8];
    prm.gamma   = (const float*)d_in[9];
    prm.beta    = (const float*)d_in[10];
    prm.mean    = (const float*)d_in[11];
    prm.var     = (const float*)d_in[12];
    prm.out     = (float*)d_out;

    prm.spart = (float*)(wsb + 0);          // 200704 B
    prm.slv   = (float*)(wsb + 204800);     // 4 KB
    prm.qarr  = (float*)(wsb + 208896);     // 4 KB
    prm.Ls    = (float*)(wsb + 212992);     // 4 KB
    prm.pv    = (float*)(wsb + 217088);     // 1 KB
    prm.tgg   = (float*)(wsb + 221184);     // 1 KB
    prm.wtg   = (float*)(wsb + 225280);     // 1 KB
    prm.bnc   = (float*)(wsb + 229376);     // 1 KB
    prm.swt   = (float*)(wsb + 233472);     // 16 B
    prm.scal  = (float*)(wsb + 237568);     // 4 B
    prm.bias5 = (float*)(wsb + 241664);     // 4 KB
    prm.Gbf   = (short*)(wsb + 262144);     // 512 KB
    prm.Ut    = (short*)(wsb + 786432);     // 256 KB
    prm.T2t   = (short*)(wsb + 1048576);    // 128 KB
    prm.T3    = (short*)(wsb + 1179648);    // 256 KB
    prm.WtT   = (short*)(wsb + 1441792);    // 64 KB
    prm.W5    = (short*)(wsb + 1572864);    // 512 KB
    prm.xbf   = (short*)(wsb + 2097152);    // 6.42 MB
    prm.xT    = (short*)(wsb + 16777216);   // 6.42 MB

    void* args[] = { &prm };
    hipLaunchCooperativeKernel((const void*)mono_kernel, dim3(256), dim3(256),
                               args, 0, stream);
}

// Round 10
// 175.833 us; speedup vs baseline: 1.5571x; 1.5571x over previous
//
#include <hip/hip_runtime.h>

#define B 4
#define C 256
#define CI 128
#define NPIX 3136      // 56*56 = 49 * 64
#define BN_EPS_F 1e-5f
#define INVN (1.0f / 3136.0f)

typedef float f4 __attribute__((ext_vector_type(4)));
typedef float f32x4 __attribute__((ext_vector_type(4)));
typedef short short8 __attribute__((ext_vector_type(8)));
typedef short short4v __attribute__((ext_vector_type(4)));
typedef unsigned int u32;

__device__ inline short f2bf(float f) {
    u32 u = __builtin_bit_cast(u32, f);
    u32 r = (u + 0x7FFFu + ((u >> 16) & 1u)) >> 16;
    return (short)r;
}
__device__ inline float bf2f(short v) {
    u32 u = ((u32)(unsigned short)v) << 16;
    return __builtin_bit_cast(float, u);
}
// XOR-swizzle for [32][256] bf16 LDS tile (rows 512 B): spread 8 rows over 8
// 16B slots so 16-lane column reads don't hit one bank (G4).
__device__ inline int hoff(int row, int col) {
    return ((row * 256 + col) * 2) ^ ((row & 7) << 4);
}

// ---- prep: blocks 0..783 tiles (xbf, xT, spart[b][nb][c]); block 784 = vec ----
__global__ __launch_bounds__(256) void prep_kernel(
        const float* __restrict__ x,
        const float* __restrict__ wrec, const float* __restrict__ wphi,
        const float* __restrict__ wtheta,
        const float* __restrict__ gamma, const float* __restrict__ var,
        const float* __restrict__ bg, const float* __restrict__ bphi,
        const float* __restrict__ btheta, const float* __restrict__ brec,
        const float* __restrict__ beta, const float* __restrict__ mean,
        short* __restrict__ xbf, short* __restrict__ xT,
        float* __restrict__ spart,
        float* __restrict__ pv, float* __restrict__ tgg, float* __restrict__ wtg,
        float* __restrict__ bnc, float* __restrict__ scal) {
    int bid = blockIdx.x;
    int t = threadIdx.x;
    if (bid < 784) {
        int nb = bid % 49, cb = (bid / 49) & 3, b = bid / 196;
        int n0 = nb * 64, c0 = cb * 64;
        __shared__ short lds[64][65];
        int nf = (t & 15) * 4, cr = t >> 4;
        float psum[4];
#pragma unroll
        for (int it = 0; it < 4; ++it) {
            int c = cr + 16 * it;
            f4 v = *(const f4*)&x[((size_t)(b * C + c0 + c)) * NPIX + n0 + nf];
            short4v s4;
            float ps = 0.f;
#pragma unroll
            for (int i = 0; i < 4; ++i) { s4[i] = f2bf(v[i]); ps += v[i]; }
            psum[it] = ps;
            *(short4v*)&xbf[((size_t)(b * C + c0 + c)) * NPIX + n0 + nf] = s4;
#pragma unroll
            for (int i = 0; i < 4; ++i) lds[nf + i][c] = s4[i];
        }
#pragma unroll
        for (int it = 0; it < 4; ++it) {
            float ps = psum[it];
#pragma unroll
            for (int m = 8; m >= 1; m >>= 1) ps += __shfl_xor(ps, m, 64);
            if ((t & 15) == 0)
                spart[((size_t)b * 49 + nb) * C + c0 + cr + 16 * it] = ps;
        }
        __syncthreads();
#pragma unroll
        for (int it = 0; it < 4; ++it) {
            int n = cr + 16 * it;
            short4v s4;
#pragma unroll
            for (int i = 0; i < 4; ++i) s4[i] = lds[n][nf + i];
            *(short4v*)&xT[((size_t)b * NPIX + n0 + n) * C + c0 + nf] = s4;
        }
    } else {
        // vec: pv, tgg, wtg, bnc, scal[0]=bphi.btheta  (lean: unroll<=4)
        __shared__ float red[4];
        float inv_t = gamma[t] * rsqrtf(var[t] + BN_EPS_F);
        float accp = 0.f;
#pragma unroll 4
        for (int j4 = 0; j4 < CI; j4 += 4) {
            f4 w = *(const f4*)&wrec[t * CI + j4];
            f4 g4 = *(const f4*)&bg[j4];
            accp += w[0] * g4[0] + w[1] * g4[1] + w[2] * g4[2] + w[3] * g4[3];
        }
        pv[t] = inv_t * accp;
        float at = 0.f, aw = 0.f;
        for (int i = 0; i < CI; ++i) {
            at = fmaf(wtheta[i * C + t], bphi[i], at);
            aw = fmaf(wphi[i * C + t], btheta[i], aw);
        }
        tgg[t] = at;
        wtg[t] = aw;
        bnc[t] = inv_t * brec[t] + beta[t] - mean[t] * inv_t;
        float cp = (t < CI) ? bphi[t] * btheta[t] : 0.f;
#pragma unroll
        for (int m = 32; m >= 1; m >>= 1) cp += __shfl_xor(cp, m, 64);
        if ((t & 63) == 0) red[t >> 6] = cp;
        __syncthreads();
        if (t == 0) scal[0] = red[0] + red[1] + red[2] + red[3];
    }
}

// ---- wk: blocks 0..15 L = diag(inv)·wrec·Wg; 16..31 Rt = Wθᵀ·Wφ (both bf16 out)
__global__ __launch_bounds__(256) void wk_kernel(
        const float* __restrict__ wrec, const float* __restrict__ wg,
        const float* __restrict__ wtheta, const float* __restrict__ wphi,
        const float* __restrict__ gamma, const float* __restrict__ var,
        short* __restrict__ Lbf, short* __restrict__ Rtbf) {
    __shared__ float wl[64][68];
    __shared__ float xl[64][68];
    int bid = blockIdx.x;
    bool isL = bid < 16;
    int bi = bid & 15;
    int i0 = (bi >> 2) * 64, j0 = (bi & 3) * 64;
    int t = threadIdx.x, tx = t & 15, ty = t >> 4;
    float acc[4][4] = {};
    for (int k0 = 0; k0 < CI; k0 += 64) {
        __syncthreads();
        if (isL) {
#pragma unroll
            for (int l = 0; l < 4; ++l) {
                int idx = t + l * 256;
                int r = idx >> 4, c4 = (idx & 15) << 2;
                *(f4*)&wl[r][c4] = *(const f4*)&wrec[(i0 + r) * CI + k0 + c4];
                *(f4*)&xl[r][c4] = *(const f4*)&wg[(size_t)(k0 + r) * C + j0 + c4];
            }
        } else {
#pragma unroll
            for (int l = 0; l < 4; ++l) {
                int idx = t + l * 256;
                int jl = idx >> 4, cf4 = (idx & 15) << 2;
                f4 v = *(const f4*)&wtheta[(size_t)(k0 + jl) * C + i0 + cf4];
#pragma unroll
                for (int i = 0; i < 4; ++i) wl[cf4 + i][jl] = v[i];
                *(f4*)&xl[jl][cf4] = *(const f4*)&wphi[(size_t)(k0 + jl) * C + j0 + cf4];
            }
        }
        __syncthreads();
        for (int kk = 0; kk < 64; kk += 4) {
            f4 a[4], bb[4];
#pragma unroll
            for (int i = 0; i < 4; ++i) a[i] = *(const f4*)&wl[ty + 16 * i][kk];
#pragma unroll
            for (int q = 0; q < 4; ++q) bb[q] = *(const f4*)&xl[kk + q][tx * 4];
#pragma unroll
            for (int q = 0; q < 4; ++q)
#pragma unroll
                for (int i = 0; i < 4; ++i)
#pragma unroll
                    for (int j = 0; j < 4; ++j)
                        acc[i][j] += a[i][q] * bb[q][j];
        }
    }
    short* dst = isL ? Lbf : Rtbf;
#pragma unroll
    for (int i = 0; i < 4; ++i) {
        int r = i0 + ty + 16 * i;
        float scale = isL ? gamma[r] * rsqrtf(var[r] + BN_EPS_F) : 1.0f;
#pragma unroll
        for (int j = 0; j < 4; ++j)
            dst[r * C + j0 + tx * 4 + j] = f2bf(scale * acc[i][j]);
    }
}

// ---- xxt: Gbf[b] = bf16(x x^T). grid (4,4,B), 512t (r8 verbatim, healthy) ----
__global__ __launch_bounds__(512) void xxt_kernel(const short* __restrict__ xbf,
                                                  short* __restrict__ Gbf) {
    __shared__ float gred[4][32][33];
    int b = blockIdx.z;
    int t = threadIdx.x, lane = t & 63, wid = t >> 6;
    int sub = wid & 3, kc = wid >> 2;
    int ibase = blockIdx.y * 64 + (sub >> 1) * 32;
    int jbase = blockIdx.x * 64 + (sub & 1) * 32;
    int lm = lane & 15, lk = (lane >> 4) * 8, r0 = (lane >> 4) * 4;
    const short* A0 = xbf + ((size_t)(b * C) + ibase + lm) * NPIX;
    const short* B0 = xbf + ((size_t)(b * C) + jbase + lm) * NPIX;
    f32x4 acc[2][2] = {};
    int k0 = kc * 1568, k1 = k0 + 1568;
    for (int k = k0; k < k1; k += 32) {
        short8 av[2], bv[2];
#pragma unroll
        for (int mi = 0; mi < 2; ++mi) av[mi] = *(const short8*)(A0 + (size_t)mi * 16 * NPIX + k + lk);
#pragma unroll
        for (int nj = 0; nj < 2; ++nj) bv[nj] = *(const short8*)(B0 + (size_t)nj * 16 * NPIX + k + lk);
#pragma unroll
        for (int mi = 0; mi < 2; ++mi)
#pragma unroll
            for (int nj = 0; nj < 2; ++nj)
                acc[mi][nj] = __builtin_amdgcn_mfma_f32_16x16x32_bf16(av[mi], bv[nj], acc[mi][nj], 0, 0, 0);
    }
    if (kc == 0) {
#pragma unroll
        for (int mi = 0; mi < 2; ++mi)
#pragma unroll
            for (int nj = 0; nj < 2; ++nj)
#pragma unroll
                for (int r = 0; r < 4; ++r)
                    gred[sub][mi * 16 + r0 + r][nj * 16 + lm] = acc[mi][nj][r];
    }
    __syncthreads();
    if (kc == 1) {
        short* Gb = Gbf + (size_t)b * C * C;
#pragma unroll
        for (int mi = 0; mi < 2; ++mi)
#pragma unroll
            for (int nj = 0; nj < 2; ++nj)
#pragma unroll
                for (int r = 0; r < 4; ++r) {
                    float v = acc[mi][nj][r] + gred[sub][mi * 16 + r0 + r][nj * 16 + lm];
                    Gb[(ibase + mi * 16 + r0 + r) * C + jbase + nj * 16 + lm] = f2bf(v);
                }
    }
}

// ---- hw5: grid (8, B), 256t. 32-row o-strip: H=L·G → LDS; W5=H·Rt + bias5 ----
__global__ __launch_bounds__(256) void hw5_kernel(
        const short* __restrict__ Lbf, const short* __restrict__ Rtbf,
        const short* __restrict__ Gbf, const float* __restrict__ spart,
        const float* __restrict__ pv, const float* __restrict__ tgg,
        const float* __restrict__ wtg, const float* __restrict__ bnc,
        const float* __restrict__ scal,
        short* __restrict__ W5bf, float* __restrict__ bias5) {
    int o0 = blockIdx.x * 32, b = blockIdx.y;
    __shared__ char Hl[32 * 256 * 2];              // 16 KB swizzled bf16
    __shared__ float sl[C], wtl[C], tgl[C], qarr[C];
    __shared__ float Lsp[8][32], biasp[8][32], LsS[32], pvS[32], redsw[4];
    int t = threadIdx.x, lane = t & 63, wid = t >> 6;
    int lm = lane & 15, lk = (lane >> 4) * 8, r0q = (lane >> 4) * 4;

    // S: stage sl (coalesced spart[b][i][c]), wtl, tgl, pvS
    {
        float sv = 0.f;
        for (int i = 0; i < 49; ++i) sv += spart[((size_t)b * 49 + i) * C + t];
        sl[t] = sv; wtl[t] = wtg[t]; tgl[t] = tgg[t];
        if (t < 32) pvS[t] = pv[o0 + t];
    }
    __syncthreads();

    // P1: per wave H[32 o][64 c], K=256 (G symmetric → B rows = G rows)
    {
        int cw = wid * 64;
        f32x4 acc[2][4] = {};
        const short* Gb = Gbf + (size_t)b * C * C;
        for (int k = 0; k < C; k += 32) {
            short8 av[2], bv[4];
#pragma unroll
            for (int mi = 0; mi < 2; ++mi)
                av[mi] = *(const short8*)(Lbf + (size_t)(o0 + mi * 16 + lm) * C + k + lk);
#pragma unroll
            for (int nj = 0; nj < 4; ++nj)
                bv[nj] = *(const short8*)(Gb + (size_t)(cw + nj * 16 + lm) * C + k + lk);
#pragma unroll
            for (int mi = 0; mi < 2; ++mi)
#pragma unroll
                for (int nj = 0; nj < 4; ++nj)
                    acc[mi][nj] = __builtin_amdgcn_mfma_f32_16x16x32_bf16(av[mi], bv[nj], acc[mi][nj], 0, 0, 0);
        }
#pragma unroll
        for (int mi = 0; mi < 2; ++mi)
#pragma unroll
            for (int rr = 0; rr < 4; ++rr)
#pragma unroll
                for (int nj = 0; nj < 4; ++nj)
                    *(short*)(Hl + hoff(mi * 16 + r0q + rr, cw + nj * 16 + lm)) = f2bf(acc[mi][nj][rr]);
    }
    __syncthreads();

    // V: qarr[cp] = Rt[cp]·s ; Ls/biasH strip partials ; swt
    {
        const short8* rr = (const short8*)(Rtbf + (size_t)t * C);
        float a = 0.f;
        for (int c8 = 0; c8 < 32; ++c8) {
            short8 v = rr[c8];
#pragma unroll
            for (int i = 0; i < 8; ++i) a += bf2f(v[i]) * sl[c8 * 8 + i];
        }
        qarr[t] = a;
    }
    {
        int ol = t & 31, qq = t >> 5;           // 8 chunks of 32 cols
        const short8* lr = (const short8*)(Lbf + (size_t)(o0 + ol) * C + qq * 32);
        float a = 0.f;
#pragma unroll
        for (int c8 = 0; c8 < 4; ++c8) {
            short8 v = lr[c8];
#pragma unroll
            for (int i = 0; i < 8; ++i) a += bf2f(v[i]) * sl[qq * 32 + c8 * 8 + i];
        }
        Lsp[qq][ol] = a;
        float bh = 0.f;
        for (int c = 0; c < 32; ++c) {
            int cc = qq * 32 + c;
            bh += bf2f(*(const short*)(Hl + hoff(ol, cc))) * wtl[cc];
        }
        biasp[qq][ol] = bh;
    }
    {
        float part = sl[t] * wtl[t];
#pragma unroll
        for (int m = 32; m >= 1; m >>= 1) part += __shfl_xor(part, m, 64);
        if ((t & 63) == 0) redsw[t >> 6] = part;
    }
    __syncthreads();

    // bias5 + LsS
    if (t < 32) {
        float ls = 0.f, bh = 0.f;
#pragma unroll
        for (int qq = 0; qq < 8; ++qq) { ls += Lsp[qq][t]; bh += biasp[qq][t]; }
        LsS[t] = ls;
        float swtv = redsw[0] + redsw[1] + redsw[2] + redsw[3];
        int o = o0 + t;
        bias5[b * C + o] = INVN * bh + INVN * swtv * pvS[t]
                         + scal[0] * (INVN * ls + pvS[t]) + bnc[o];
    }
    __syncthreads();

    // P2: per wave W5[32 o][64 cp], K=256 (A from LDS H, B rows = Rt rows)
    {
        int cpw = wid * 64;
        f32x4 acc[2][4] = {};
        for (int k = 0; k < C; k += 32) {
            short8 av[2], bv[4];
#pragma unroll
            for (int mi = 0; mi < 2; ++mi)
                av[mi] = *(const short8*)(Hl + hoff(mi * 16 + lm, k + lk));
#pragma unroll
            for (int nj = 0; nj < 4; ++nj)
                bv[nj] = *(const short8*)(Rtbf + (size_t)(cpw + nj * 16 + lm) * C + k + lk);
#pragma unroll
            for (int mi = 0; mi < 2; ++mi)
#pragma unroll
                for (int nj = 0; nj < 4; ++nj)
                    acc[mi][nj] = __builtin_amdgcn_mfma_f32_16x16x32_bf16(av[mi], bv[nj], acc[mi][nj], 0, 0, 0);
        }
        short* Wb = W5bf + (size_t)b * C * C;
#pragma unroll
        for (int mi = 0; mi < 2; ++mi) {
#pragma unroll
            for (int rr = 0; rr < 4; ++rr) {
                int ol = mi * 16 + r0q + rr;
                float po = pvS[ol], ls = LsS[ol];
#pragma unroll
                for (int nj = 0; nj < 4; ++nj) {
                    int cp = cpw + nj * 16 + lm;
                    float w5 = INVN * acc[mi][nj][rr]
                             + po * (INVN * qarr[cp] + tgl[cp])
                             + INVN * ls * tgl[cp];
                    Wb[(o0 + ol) * C + cp] = f2bf(w5);
                }
            }
        }
    }
}

// ---- final: out = W5·x + bias5 + x. grid (49, B), 256t ----
__global__ __launch_bounds__(256) void final_mfma(const float* __restrict__ x,
                                                  const short* __restrict__ W5bf,
                                                  const short* __restrict__ xT,
                                                  const float* __restrict__ bias5,
                                                  float* __restrict__ out) {
    int b = blockIdx.y;
    int n0 = blockIdx.x * 64;
    int tid = threadIdx.x, lane = tid & 63, wid = tid >> 6;
    int obase = wid * 64;
    int lm = lane & 15, lk = (lane >> 4) * 8;
    const short* A0 = W5bf + ((size_t)(b * C) + obase + lm) * C + lk;
    const short* B0 = xT + ((size_t)b * NPIX + n0 + lm) * C + lk;
    f32x4 acc[4][4] = {};
#pragma unroll
    for (int k = 0; k < C; k += 32) {
        short8 a[4], bv[4];
#pragma unroll
        for (int mi = 0; mi < 4; ++mi) a[mi] = *(const short8*)(A0 + mi * 16 * C + k);
#pragma unroll
        for (int nj = 0; nj < 4; ++nj) bv[nj] = *(const short8*)(B0 + nj * 16 * C + k);
#pragma unroll
        for (int mi = 0; mi < 4; ++mi)
#pragma unroll
            for (int nj = 0; nj < 4; ++nj)
                acc[mi][nj] = __builtin_amdgcn_mfma_f32_16x16x32_bf16(a[mi], bv[nj], acc[mi][nj], 0, 0, 0);
    }
    int r0 = (lane >> 4) * 4;
#pragma unroll
    for (int mi = 0; mi < 4; ++mi) {
#pragma unroll
        for (int rr = 0; rr < 4; ++rr) {
            int o = obase + mi * 16 + r0 + rr;
            float bias = bias5[b * C + o];
            const float* xrow = x + ((size_t)(b * C + o)) * NPIX;
            float* orow = out + ((size_t)(b * C + o)) * NPIX;
#pragma unroll
            for (int nj = 0; nj < 4; ++nj) {
                int n = n0 + nj * 16 + lm;
                orow[n] = acc[mi][nj][rr] + bias + xrow[n];
            }
        }
    }
}

extern "C" void kernel_launch(void* const* d_in, const int* in_sizes, int n_in,
                              void* d_out, int out_size, void* d_ws, size_t ws_size,
                              hipStream_t stream) {
    const float* x       = (const float*)d_in[0];
    const float* w_theta = (const float*)d_in[1];
    const float* b_theta = (const float*)d_in[2];
    const float* w_phi   = (const float*)d_in[3];
    const float* b_phi   = (const float*)d_in[4];
    const float* w_g     = (const float*)d_in[5];
    const float* b_g     = (const float*)d_in[6];
    const float* w_rec   = (const float*)d_in[7];
    const float* b_rec   = (const float*)d_in[8];
    const float* gamma   = (const float*)d_in[9];
    const float* beta    = (const float*)d_in[10];
    const float* mean    = (const float*)d_in[11];
    const float* var     = (const float*)d_in[12];
    float* out = (float*)d_out;

    char* wsb = (char*)d_ws;
    float* spart = (float*)(wsb + 0);          // 4*49*256 f32 = 200704 B
    float* pv    = (float*)(wsb + 204800);
    float* tgg   = (float*)(wsb + 205824);
    float* wtg   = (float*)(wsb + 206848);
    float* bnc   = (float*)(wsb + 207872);
    float* scal  = (float*)(wsb + 208896);
    float* bias5 = (float*)(wsb + 212992);     // 4 KB
    short* Lbf   = (short*)(wsb + 262144);     // 128 KB
    short* Rtbf  = (short*)(wsb + 393216);     // 128 KB
    short* Gbf   = (short*)(wsb + 524288);     // 512 KB
    short* W5bf  = (short*)(wsb + 1048576);    // 512 KB
    short* xbf   = (short*)(wsb + 2097152);    // 6.42 MB
    short* xT    = (short*)(wsb + 16777216);   // 6.42 MB

    prep_kernel<<<dim3(785), dim3(256), 0, stream>>>(
        x, w_rec, w_phi, w_theta, gamma, var, b_g, b_phi, b_theta,
        b_rec, beta, mean, xbf, xT, spart, pv, tgg, wtg, bnc, scal);
    wk_kernel<<<dim3(32), dim3(256), 0, stream>>>(
        w_rec, w_g, w_theta, w_phi, gamma, var, Lbf, Rtbf);
    xxt_kernel<<<dim3(4, 4, B), dim3(512), 0, stream>>>(xbf, Gbf);
    hw5_kernel<<<dim3(8, B), dim3(256), 0, stream>>>(
        Lbf, Rtbf, Gbf, spart, pv, tgg, wtg, bnc, scal, W5bf, bias5);
    final_mfma<<<dim3(NPIX / 64, B), dim3(256), 0, stream>>>(x, W5bf, xT, bias5, out);
}